// Round 7
// baseline (70.814 us; speedup 1.0000x reference)
//
#include <hip/hip_runtime.h>

// Problem constants: B=128, N=64, D=64
// Outputs (flat): kappa [B,N,N]=524288, diff [B,N,N,D]=33554432,
//                 gamma [B,1,1,1]=128, kappa_grad [B,N,N,D]=33554432
//
//  k1 (1024 blocks): blocks 0..127  -> per-batch d2 (regs) -> exact lower
//                    median -> gamma; kappa = exp(-g*d2) via LDS, coalesced.
//                    blocks 128..1023 -> diff rows [0, 2688)
//  k2 (2048 blocks): pure streaming: diff rows [2688,8192) + all kappa_grad.
//                    No shfl, no expf -> store issue never stalls.

#define NBATCH   128
#define K1_GRID  1024
#define K1_WROWS 3
#define K1_ROWS  2688   // (1024-128)*3
#define K2_RPB   4      // rows per block in k2

typedef float f32x4 __attribute__((ext_vector_type(4)));

__device__ __forceinline__ void nt_store4(float* p, float x, float y, float z, float w) {
    f32x4 v = {x, y, z, w};
    __builtin_nontemporal_store(v, reinterpret_cast<f32x4*>(p));
}

__global__ __launch_bounds__(256) void rbf_k1(
    const float* __restrict__ in1, const float* __restrict__ in2,
    float* __restrict__ out_diff, float* __restrict__ out_gamma,
    float* __restrict__ out_kappa)
{
    // 32 KB shared: A^T,B^T during dist^2; reused as histogram, then as kappa
    __shared__ float smem[2 * 64 * 64];
    __shared__ int   sWave[4];
    __shared__ int   sSel[2];
    __shared__ float sGamma;

    const int p    = blockIdx.x;
    const int t    = threadIdx.x;
    const int wave = t >> 6;
    const int lane = t & 63;

    if (p >= NBATCH) {
        // ---- diff writer: rows 3*(p-128) .. +2 ----
        const int jo = lane >> 4;
        const int q  = lane & 15;
        const int d4 = q << 2;
        const int w  = p - NBATCH;
        for (int r = 0; r < K1_WROWS; ++r) {
            const int bi = w * K1_WROWS + r;
            const int b  = bi >> 6;
            const float4 a4 = *reinterpret_cast<const float4*>(in1 + ((size_t)bi << 6) + d4);
            const float* in2b = in2 + ((size_t)b << 12);
            float* diffBase = out_diff + ((size_t)bi << 12);
            #pragma unroll
            for (int it = 0; it < 4; ++it) {
                int j = wave * 16 + it * 4 + jo;
                float4 b4 = *reinterpret_cast<const float4*>(in2b + (j << 6) + d4);
                nt_store4(diffBase + (j << 6) + d4,
                          a4.x - b4.x, a4.y - b4.y, a4.z - b4.z, a4.w - b4.w);
            }
        }
        return;
    }

    // ---- median + kappa for batch p ----
    float* sAT = smem;            // [d][i], stride 64
    float* sBT = smem + 4096;     // [d][j], stride 64

    const float* A  = in1 + p * 4096;
    const float* Bv = in2 + p * 4096;

    for (int e = t; e < 1024; e += 256) {
        int i = e >> 4, d0 = (e & 15) << 2;
        float4 av = *reinterpret_cast<const float4*>(A  + (i << 6) + d0);
        float4 bv = *reinterpret_cast<const float4*>(Bv + (i << 6) + d0);
        sAT[(d0+0)*64 + i] = av.x; sAT[(d0+1)*64 + i] = av.y;
        sAT[(d0+2)*64 + i] = av.z; sAT[(d0+3)*64 + i] = av.w;
        sBT[(d0+0)*64 + i] = bv.x; sBT[(d0+1)*64 + i] = bv.y;
        sBT[(d0+2)*64 + i] = bv.z; sBT[(d0+3)*64 + i] = bv.w;
    }
    __syncthreads();

    // 4x4 register tile: i0 = 4*(t>>4), j0 = 4*(t&15)
    const int i0 = (t >> 4) << 2;
    const int j0 = (t & 15) << 2;
    float acc[4][4];
    #pragma unroll
    for (int r = 0; r < 4; ++r)
        #pragma unroll
        for (int c = 0; c < 4; ++c) acc[r][c] = 0.f;

    #pragma unroll 8
    for (int d = 0; d < 64; ++d) {
        float4 av = *reinterpret_cast<const float4*>(&sAT[d * 64 + i0]);
        float4 bv = *reinterpret_cast<const float4*>(&sBT[d * 64 + j0]);
        float ar[4] = {av.x, av.y, av.z, av.w};
        float bc[4] = {bv.x, bv.y, bv.z, bv.w};
        #pragma unroll
        for (int r = 0; r < 4; ++r)
            #pragma unroll
            for (int c = 0; c < 4; ++c) {
                float df = ar[r] - bc[c];
                acc[r][c] = fmaf(df, df, acc[r][c]);
            }
    }

    unsigned uv[16];
    #pragma unroll
    for (int r = 0; r < 4; ++r)
        #pragma unroll
        for (int c = 0; c < 4; ++c) uv[r * 4 + c] = __float_as_uint(acc[r][c]);

    __syncthreads();                 // LDS reads done; smem reused as hist
    int* hist = reinterpret_cast<int*>(smem);

    bool act[16];
    #pragma unroll
    for (int x = 0; x < 16; ++x) act[x] = true;

    int need = 2047;                 // zero-based lower median of 4096
    unsigned result = 0;

    const int shifts[3] = {19, 7, 0};
    const int nbits [3] = {12, 12, 7};
    for (int lv = 0; lv < 3; ++lv) {
        const int      sh   = shifts[lv];
        const unsigned mask = (1u << nbits[lv]) - 1u;
        const int      NB_  = 1 << nbits[lv];

        for (int x = t; x < NB_; x += 256) hist[x] = 0;
        __syncthreads();
        #pragma unroll
        for (int x = 0; x < 16; ++x)
            if (act[x]) atomicAdd(&hist[(uv[x] >> sh) & mask], 1);
        __syncthreads();

        int lbins[16]; int lsum = 0;
        #pragma unroll
        for (int x = 0; x < 16; ++x) {
            int idx = t * 16 + x;
            int h = (idx < NB_) ? hist[idx] : 0;
            lbins[x] = h; lsum += h;
        }
        int v = lsum;
        #pragma unroll
        for (int off = 1; off < 64; off <<= 1) {
            int o = __shfl_up(v, off, 64);
            if (lane >= off) v += o;
        }
        if (lane == 63) sWave[wave] = v;
        __syncthreads();
        int woff = 0;
        for (int w2 = 0; w2 < wave; ++w2) woff += sWave[w2];
        int excl = woff + v - lsum;
        if (lsum > 0 && need >= excl && need < excl + lsum) {
            int acc2 = excl;
            #pragma unroll
            for (int x = 0; x < 16; ++x) {
                if (need < acc2 + lbins[x]) { sSel[0] = t*16 + x; sSel[1] = need - acc2; break; }
                acc2 += lbins[x];
            }
        }
        __syncthreads();
        int bin = sSel[0]; need = sSel[1];
        result |= ((unsigned)bin) << sh;
        #pragma unroll
        for (int x = 0; x < 16; ++x)
            act[x] = act[x] && (((uv[x] >> sh) & mask) == (unsigned)bin);
        __syncthreads();
    }

    if (t == 0) {
        float med   = __uint_as_float(result);       // exact sorted[2047]
        float h     = med / (2.0f * logf(64.0f + 1.0f));
        float sigma = sqrtf(h);
        float gamma = 1.0f / (1e-8f + 2.0f * sigma * sigma);
        out_gamma[p] = gamma;
        sGamma       = gamma;
    }
    __syncthreads();

    // ---- kappa for this batch: regs -> LDS -> coalesced float4 stores ----
    const float gamma = sGamma;
    float* kapS = smem;              // 4096 floats [i][j]
    #pragma unroll
    for (int r = 0; r < 4; ++r)
        #pragma unroll
        for (int c = 0; c < 4; ++c)
            kapS[(i0 + r) * 64 + (j0 + c)] = __expf(-gamma * acc[r][c]);
    __syncthreads();
    float* kapBase = out_kappa + ((size_t)p << 12);
    for (int e = t; e < 1024; e += 256) {
        float4 v = reinterpret_cast<const float4*>(kapS)[e];
        nt_store4(kapBase + (e << 2), v.x, v.y, v.z, v.w);
    }
}

// ---- k2: pure streaming diff + kappa_grad (no shfl, no expf) ----
__global__ __launch_bounds__(256) void rbf_k2(
    const float* __restrict__ in1, const float* __restrict__ in2,
    const float* __restrict__ gsrc, const float* __restrict__ kappa,
    float* __restrict__ out_diff, float* __restrict__ out_kgrad)
{
    const int t    = threadIdx.x;
    const int wave = t >> 6;
    const int lane = t & 63;
    const int jo   = lane >> 4;
    const int q    = lane & 15;
    const int d4   = q << 2;
    const int blk  = blockIdx.x;
    const int b    = blk >> 4;            // 16 blocks per batch (4 rows each)

    const float  gamma = gsrc[b];
    const float  m0    = -2.0f * gamma;
    const float* in2b  = in2 + ((size_t)b << 12);

    for (int r = 0; r < K2_RPB; ++r) {
        const int bi = blk * K2_RPB + r;
        const float4 a4 = *reinterpret_cast<const float4*>(in1 + ((size_t)bi << 6) + d4);
        const float* kapRow = kappa + ((size_t)bi << 6);
        float* diffBase = out_diff  + ((size_t)bi << 12);
        float* kgBase   = out_kgrad + ((size_t)bi << 12);
        const bool doDiff = (bi >= K1_ROWS);
        #pragma unroll
        for (int it = 0; it < 4; ++it) {
            int j = wave * 16 + it * 4 + jo;
            float4 b4 = *reinterpret_cast<const float4*>(in2b + (j << 6) + d4);
            float kap = kapRow[j];
            float4 df;
            df.x = a4.x - b4.x; df.y = a4.y - b4.y;
            df.z = a4.z - b4.z; df.w = a4.w - b4.w;
            if (doDiff)
                nt_store4(diffBase + (j << 6) + d4, df.x, df.y, df.z, df.w);
            float m = m0 * kap;
            nt_store4(kgBase + (j << 6) + d4, m * df.x, m * df.y, m * df.z, m * df.w);
        }
    }
}

extern "C" void kernel_launch(void* const* d_in, const int* in_sizes, int n_in,
                              void* d_out, int out_size, void* d_ws, size_t ws_size,
                              hipStream_t stream) {
    const float* in1 = (const float*)d_in[0];
    const float* in2 = (const float*)d_in[1];
    float* out = (float*)d_out;

    float* out_kappa = out;                              // 524288
    float* out_diff  = out + 524288;                     // 33554432
    float* out_gamma = out + 524288 + 33554432;          // 128
    float* out_kgrad = out_gamma + 128;                  // 33554432

    rbf_k1<<<K1_GRID,           256, 0, stream>>>(in1, in2, out_diff, out_gamma, out_kappa);
    rbf_k2<<<8192 / K2_RPB,     256, 0, stream>>>(in1, in2, out_gamma, out_kappa,
                                                  out_diff, out_kgrad);
}